// Round 1
// baseline (208.681 us; speedup 1.0000x reference)
//
#include <hip/hip_runtime.h>
#include <stdint.h>

#define C_DIM 64
#define N_POS 4096
#define B_SZ  4
#define QBLK  64
#define KVBLK 64
#define NKV   (N_POS / KVBLK)

typedef __attribute__((ext_vector_type(8))) short short8;
typedef __attribute__((ext_vector_type(4))) short short4v;
typedef __attribute__((ext_vector_type(4))) float f32x4;

static __device__ __forceinline__ short f2bf(float f) {
    union { float f; uint32_t u; } cv; cv.f = f;
    uint32_t u = cv.u;
    u += 0x7fffu + ((u >> 16) & 1u);   // RNE to bf16
    return (short)(u >> 16);
}

// ---------------------------------------------------------------------------
// Projection: q/k/v = W*x + b.  x: [B][64][N] f32.
// Outputs (bf16): Qg,Kg as [B][N][64]; Vg as [B][64][N] (i.e. V^T ready).
// 512 threads: p = tid&63 (position), oct = tid>>6 (8 channels each).
// W reads are wave-uniform (readfirstlane) -> scalar loads.
// ---------------------------------------------------------------------------
static __device__ __forceinline__ void proj8(const float* __restrict__ W,
                                             const float* __restrict__ bias,
                                             const float* xv, int oct, float* acc) {
#pragma unroll
    for (int i = 0; i < 8; ++i) acc[i] = bias[oct * 8 + i];
#pragma unroll
    for (int c = 0; c < C_DIM; ++c) {
        const float xc = xv[c];
#pragma unroll
        for (int i = 0; i < 8; ++i)
            acc[i] = fmaf(W[(oct * 8 + i) * C_DIM + c], xc, acc[i]);
    }
}

__global__ __launch_bounds__(512) void proj_kernel(
    const float* __restrict__ x,
    const float* __restrict__ Wq, const float* __restrict__ bq,
    const float* __restrict__ Wk, const float* __restrict__ bk,
    const float* __restrict__ Wv, const float* __restrict__ bv,
    ushort* __restrict__ Qg, ushort* __restrict__ Kg, ushort* __restrict__ Vg)
{
    const int tid  = threadIdx.x;
    const int p    = tid & 63;
    const int oct  = __builtin_amdgcn_readfirstlane(tid >> 6); // wave-uniform
    const int b    = blockIdx.x >> 6;
    const int tile = blockIdx.x & 63;
    const int n    = tile * 64 + p;

    const float* xb = x + (size_t)b * C_DIM * N_POS + n;
    float xv[C_DIM];
#pragma unroll
    for (int c = 0; c < C_DIM; ++c) xv[c] = xb[(size_t)c * N_POS];

    float acc[8];

    proj8(Wq, bq, xv, oct, acc);
    {
        uint32_t w0 = (uint32_t)(uint16_t)f2bf(acc[0]) | ((uint32_t)(uint16_t)f2bf(acc[1]) << 16);
        uint32_t w1 = (uint32_t)(uint16_t)f2bf(acc[2]) | ((uint32_t)(uint16_t)f2bf(acc[3]) << 16);
        uint32_t w2 = (uint32_t)(uint16_t)f2bf(acc[4]) | ((uint32_t)(uint16_t)f2bf(acc[5]) << 16);
        uint32_t w3 = (uint32_t)(uint16_t)f2bf(acc[6]) | ((uint32_t)(uint16_t)f2bf(acc[7]) << 16);
        *(uint4*)(Qg + ((size_t)(b * N_POS + n)) * C_DIM + oct * 8) = make_uint4(w0, w1, w2, w3);
    }
    proj8(Wk, bk, xv, oct, acc);
    {
        uint32_t w0 = (uint32_t)(uint16_t)f2bf(acc[0]) | ((uint32_t)(uint16_t)f2bf(acc[1]) << 16);
        uint32_t w1 = (uint32_t)(uint16_t)f2bf(acc[2]) | ((uint32_t)(uint16_t)f2bf(acc[3]) << 16);
        uint32_t w2 = (uint32_t)(uint16_t)f2bf(acc[4]) | ((uint32_t)(uint16_t)f2bf(acc[5]) << 16);
        uint32_t w3 = (uint32_t)(uint16_t)f2bf(acc[6]) | ((uint32_t)(uint16_t)f2bf(acc[7]) << 16);
        *(uint4*)(Kg + ((size_t)(b * N_POS + n)) * C_DIM + oct * 8) = make_uint4(w0, w1, w2, w3);
    }
    proj8(Wv, bv, xv, oct, acc);
    {
#pragma unroll
        for (int i = 0; i < 8; ++i)
            Vg[(size_t)b * C_DIM * N_POS + (size_t)(oct * 8 + i) * N_POS + n] = (ushort)f2bf(acc[i]);
    }
}

// ---------------------------------------------------------------------------
// Fused flash attention + epilogue. 4 waves, each owns 16 q rows.
// S' = K·Q^T (swapped) so lane's col (lane&15) is one q; softmax per-lane +
// 2 shfl_xor. P stays in place as B-operand of O^T = V^T·P^T.
// LDS tiles XOR-swizzled: byte ^= (row&7)<<4.
// ---------------------------------------------------------------------------
__global__ __launch_bounds__(256) void attn_kernel(
    const ushort* __restrict__ Qg, const ushort* __restrict__ Kg, const ushort* __restrict__ Vg,
    const float* __restrict__ x, const float* __restrict__ gamma,
    float* __restrict__ out)
{
    __shared__ __align__(16) char ksb[KVBLK * 128];
    __shared__ __align__(16) char vsb[C_DIM * 128];

    const int tid  = threadIdx.x;
    const int lane = tid & 63;
    const int wv   = tid >> 6;
    const int l15  = lane & 15;
    const int g    = lane >> 4;
    const int b    = blockIdx.x >> 6;
    const int qt   = blockIdx.x & 63;
    const int qrow = qt * QBLK + wv * 16 + l15;

    // Q B-fragments: lane -> row qrow, channels 8g..8g+7 (+32)
    const ushort* qb = Qg + ((size_t)b * N_POS + qrow) * C_DIM;
    const short8 qf0 = *(const short8*)(qb + 8 * g);
    const short8 qf1 = *(const short8*)(qb + 8 * g + 32);

    // staging maps: 2 x 16B per thread for each of K and V
    int kdst[2];
    const char* kgsrc[2];
    const char* vgsrc[2];
    const char* KgB = (const char*)(Kg + (size_t)b * N_POS * C_DIM);
    const char* VgB = (const char*)(Vg + (size_t)b * C_DIM * N_POS);
#pragma unroll
    for (int i = 0; i < 2; ++i) {
        const int s   = (i * 256 + tid) * 16;
        const int row = s >> 7;
        const int c16 = (s >> 4) & 7;
        kdst[i]  = (row << 7) | (((c16 ^ (row & 7)) & 7) << 4);
        kgsrc[i] = KgB + (size_t)row * 128 + c16 * 16;            // + kt*8192
        vgsrc[i] = VgB + (size_t)row * (N_POS * 2) + c16 * 16;    // + kt*128
    }

    f32x4 O[4] = {};
    float m2 = -1e30f, ell = 0.f;

    uint4 kr[2], vr[2];
#pragma unroll
    for (int i = 0; i < 2; ++i) {
        kr[i] = *(const uint4*)(kgsrc[i]);
        vr[i] = *(const uint4*)(vgsrc[i]);
    }

    for (int kt = 0; kt < NKV; ++kt) {
        __syncthreads();                 // previous tile's compute done
#pragma unroll
        for (int i = 0; i < 2; ++i) {
            *(uint4*)(ksb + kdst[i]) = kr[i];
            *(uint4*)(vsb + kdst[i]) = vr[i];
        }
        __syncthreads();                 // tile ready
        if (kt + 1 < NKV) {              // issue next-tile loads early (hide under compute)
#pragma unroll
            for (int i = 0; i < 2; ++i) {
                kr[i] = *(const uint4*)(kgsrc[i] + (size_t)(kt + 1) * (KVBLK * 128));
                vr[i] = *(const uint4*)(vgsrc[i] + (size_t)(kt + 1) * (KVBLK * 2));
            }
        }

        // ---- S' = K · Q^T  (S'[krow, q]) ----
        f32x4 S[4] = {};
#pragma unroll
        for (int t = 0; t < 4; ++t) {
            const int row = 16 * t + l15;
            const int sw  = row & 7;
            const short8 a0 = *(const short8*)(ksb + row * 128 + ((g ^ sw) << 4));
            const short8 a1 = *(const short8*)(ksb + row * 128 + (((g + 4) ^ sw) << 4));
            S[t] = __builtin_amdgcn_mfma_f32_16x16x32_bf16(a0, qf0, S[t], 0, 0, 0);
            S[t] = __builtin_amdgcn_mfma_f32_16x16x32_bf16(a1, qf1, S[t], 0, 0, 0);
        }

        // ---- online softmax over k for this lane's q (base-2) ----
        float pm = -1e30f;
#pragma unroll
        for (int t = 0; t < 4; ++t)
#pragma unroll
            for (int r = 0; r < 4; ++r) {
                S[t][r] *= 1.4426950408889634f;
                pm = fmaxf(pm, S[t][r]);
            }
        pm = fmaxf(pm, __shfl_xor(pm, 16));
        pm = fmaxf(pm, __shfl_xor(pm, 32));
        const float mnew  = fmaxf(m2, pm);
        const float scale = exp2f(m2 - mnew);
        float ls = 0.f;
#pragma unroll
        for (int t = 0; t < 4; ++t)
#pragma unroll
            for (int r = 0; r < 4; ++r) {
                const float pv = exp2f(S[t][r] - mnew);
                S[t][r] = pv;
                ls += pv;
            }
        ls += __shfl_xor(ls, 16);
        ls += __shfl_xor(ls, 32);
        ell = ell * scale + ls;
        m2  = mnew;
#pragma unroll
        for (int u = 0; u < 4; ++u)
#pragma unroll
            for (int r = 0; r < 4; ++r) O[u][r] *= scale;

        // ---- P -> bf16 B-fragments (in place: col = lane&15 = q already) ----
        short8 pb0, pb1;
#pragma unroll
        for (int j = 0; j < 8; ++j) {
            pb0[j] = f2bf(S[(j >> 2)][j & 3]);
            pb1[j] = f2bf(S[2 + (j >> 2)][j & 3]);
        }

        // ---- O^T += V^T · P^T ----
#pragma unroll
        for (int u = 0; u < 4; ++u) {
            const int cr = 16 * u + l15;
            const int sw = cr & 7;
            const char* vb = vsb + cr * 128 + (g & 1) * 8;
            const int gh = g >> 1;
#pragma unroll
            for (int h2 = 0; h2 < 2; ++h2) {
                const short4v v0 = *(const short4v*)(vb + (((gh + 4 * h2 + 0) ^ sw) << 4));
                const short4v v1 = *(const short4v*)(vb + (((gh + 4 * h2 + 2) ^ sw) << 4));
                const short8 vf = {v0[0], v0[1], v0[2], v0[3], v1[0], v1[1], v1[2], v1[3]};
                O[u] = __builtin_amdgcn_mfma_f32_16x16x32_bf16(vf, (h2 ? pb1 : pb0), O[u], 0, 0, 0);
            }
        }
    }

    // ---- epilogue: out = gamma * (O/ell) + x ----
    const float inv = 1.0f / ell;
    const float gm  = gamma[0];
#pragma unroll
    for (int u = 0; u < 4; ++u)
#pragma unroll
        for (int r = 0; r < 4; ++r) {
            const int c = 16 * u + 4 * g + r;
            const size_t idx = (size_t)b * C_DIM * N_POS + (size_t)c * N_POS + qrow;
            out[idx] = fmaf(gm, O[u][r] * inv, x[idx]);
        }
}

extern "C" void kernel_launch(void* const* d_in, const int* in_sizes, int n_in,
                              void* d_out, int out_size, void* d_ws, size_t ws_size,
                              hipStream_t stream) {
    const float* x  = (const float*)d_in[0];
    const float* Wq = (const float*)d_in[1];
    const float* bq = (const float*)d_in[2];
    const float* Wk = (const float*)d_in[3];
    const float* bk = (const float*)d_in[4];
    const float* Wv = (const float*)d_in[5];
    const float* bv = (const float*)d_in[6];
    const float* gm = (const float*)d_in[7];
    float* out = (float*)d_out;

    ushort* Qg = (ushort*)d_ws;
    ushort* Kg = Qg + (size_t)B_SZ * N_POS * C_DIM;
    ushort* Vg = Kg + (size_t)B_SZ * N_POS * C_DIM;

    proj_kernel<<<B_SZ * (N_POS / 64), 512, 0, stream>>>(x, Wq, bq, Wk, bk, Wv, bv, Qg, Kg, Vg);
    attn_kernel<<<B_SZ * (N_POS / QBLK), 256, 0, stream>>>(Qg, Kg, Vg, x, gm, out);
}

// Round 2
// 124.653 us; speedup vs baseline: 1.6741x; 1.6741x over previous
//
#include <hip/hip_runtime.h>
#include <stdint.h>

#define C_DIM 64
#define N_POS 4096
#define B_SZ  4
#define QBLK  64
#define KVBLK 64
#define NKV   (N_POS / KVBLK)
#define NQT   (N_POS / QBLK)

typedef __attribute__((ext_vector_type(8))) short short8;
typedef __attribute__((ext_vector_type(4))) short short4v;
typedef __attribute__((ext_vector_type(4))) float f32x4;

static __device__ __forceinline__ short f2bf(float f) {
    union { float f; uint32_t u; } cv; cv.f = f;
    uint32_t u = cv.u;
    u += 0x7fffu + ((u >> 16) & 1u);   // RNE to bf16
    return (short)(u >> 16);
}

// ---------------------------------------------------------------------------
// Projection: q/k/v = W*x + b.  x: [B][64][N] f32.
// Outputs (bf16): Qg,Kg as [B][N][64]; Vg as [B][64][N] (i.e. V^T ready).
// ---------------------------------------------------------------------------
static __device__ __forceinline__ void proj8(const float* __restrict__ W,
                                             const float* __restrict__ bias,
                                             const float* xv, int oct, float* acc) {
#pragma unroll
    for (int i = 0; i < 8; ++i) acc[i] = bias[oct * 8 + i];
#pragma unroll
    for (int c = 0; c < C_DIM; ++c) {
        const float xc = xv[c];
#pragma unroll
        for (int i = 0; i < 8; ++i)
            acc[i] = fmaf(W[(oct * 8 + i) * C_DIM + c], xc, acc[i]);
    }
}

__global__ __launch_bounds__(512) void proj_kernel(
    const float* __restrict__ x,
    const float* __restrict__ Wq, const float* __restrict__ bq,
    const float* __restrict__ Wk, const float* __restrict__ bk,
    const float* __restrict__ Wv, const float* __restrict__ bv,
    ushort* __restrict__ Qg, ushort* __restrict__ Kg, ushort* __restrict__ Vg)
{
    const int tid  = threadIdx.x;
    const int p    = tid & 63;
    const int oct  = __builtin_amdgcn_readfirstlane(tid >> 6); // wave-uniform
    const int b    = blockIdx.x >> 6;
    const int tile = blockIdx.x & 63;
    const int n    = tile * 64 + p;

    const float* xb = x + (size_t)b * C_DIM * N_POS + n;
    float xv[C_DIM];
#pragma unroll
    for (int c = 0; c < C_DIM; ++c) xv[c] = xb[(size_t)c * N_POS];

    float acc[8];

    proj8(Wq, bq, xv, oct, acc);
    {
        uint32_t w0 = (uint32_t)(uint16_t)f2bf(acc[0]) | ((uint32_t)(uint16_t)f2bf(acc[1]) << 16);
        uint32_t w1 = (uint32_t)(uint16_t)f2bf(acc[2]) | ((uint32_t)(uint16_t)f2bf(acc[3]) << 16);
        uint32_t w2 = (uint32_t)(uint16_t)f2bf(acc[4]) | ((uint32_t)(uint16_t)f2bf(acc[5]) << 16);
        uint32_t w3 = (uint32_t)(uint16_t)f2bf(acc[6]) | ((uint32_t)(uint16_t)f2bf(acc[7]) << 16);
        *(uint4*)(Qg + ((size_t)(b * N_POS + n)) * C_DIM + oct * 8) = make_uint4(w0, w1, w2, w3);
    }
    proj8(Wk, bk, xv, oct, acc);
    {
        uint32_t w0 = (uint32_t)(uint16_t)f2bf(acc[0]) | ((uint32_t)(uint16_t)f2bf(acc[1]) << 16);
        uint32_t w1 = (uint32_t)(uint16_t)f2bf(acc[2]) | ((uint32_t)(uint16_t)f2bf(acc[3]) << 16);
        uint32_t w2 = (uint32_t)(uint16_t)f2bf(acc[4]) | ((uint32_t)(uint16_t)f2bf(acc[5]) << 16);
        uint32_t w3 = (uint32_t)(uint16_t)f2bf(acc[6]) | ((uint32_t)(uint16_t)f2bf(acc[7]) << 16);
        *(uint4*)(Kg + ((size_t)(b * N_POS + n)) * C_DIM + oct * 8) = make_uint4(w0, w1, w2, w3);
    }
    proj8(Wv, bv, xv, oct, acc);
    {
#pragma unroll
        for (int i = 0; i < 8; ++i)
            Vg[(size_t)b * C_DIM * N_POS + (size_t)(oct * 8 + i) * N_POS + n] = (ushort)f2bf(acc[i]);
    }
}

// ---------------------------------------------------------------------------
// Fused flash attention, KV-split (flash-decoding). Each block handles one
// (b, q-tile, split) and writes UN-NORMALIZED partial O + (m, ell) to ws.
// 4 waves, 16 q rows each. Swapped QK^T; P in place as PV B-operand.
// ---------------------------------------------------------------------------
__global__ __launch_bounds__(256) void attn_kernel(
    const ushort* __restrict__ Qg, const ushort* __restrict__ Kg, const ushort* __restrict__ Vg,
    float* __restrict__ Opart, float* __restrict__ mell,
    int split, int ktiles)
{
    __shared__ __align__(16) char ksb[KVBLK * 128];
    __shared__ __align__(16) char vsb[C_DIM * 128];

    const int tid  = threadIdx.x;
    const int lane = tid & 63;
    const int wv   = tid >> 6;
    const int l15  = lane & 15;
    const int g    = lane >> 4;

    const int sp = blockIdx.x % split;
    const int bq = blockIdx.x / split;
    const int b  = bq >> 6;
    const int qt = bq & 63;
    const int kt0 = sp * ktiles;
    const int ktEnd = kt0 + ktiles;

    const int qrow = qt * QBLK + wv * 16 + l15;

    // Q B-fragments: lane -> row qrow, channels 8g..8g+7 (+32)
    const ushort* qb = Qg + ((size_t)b * N_POS + qrow) * C_DIM;
    const short8 qf0 = *(const short8*)(qb + 8 * g);
    const short8 qf1 = *(const short8*)(qb + 8 * g + 32);

    // staging maps: 2 x 16B per thread for each of K and V
    int kdst[2];
    const char* kgsrc[2];
    const char* vgsrc[2];
    const char* KgB = (const char*)(Kg + (size_t)b * N_POS * C_DIM);
    const char* VgB = (const char*)(Vg + (size_t)b * C_DIM * N_POS);
#pragma unroll
    for (int i = 0; i < 2; ++i) {
        const int s   = (i * 256 + tid) * 16;
        const int row = s >> 7;
        const int c16 = (s >> 4) & 7;
        kdst[i]  = (row << 7) | (((c16 ^ (row & 7)) & 7) << 4);
        kgsrc[i] = KgB + (size_t)row * 128 + c16 * 16;            // + kt*8192
        vgsrc[i] = VgB + (size_t)row * (N_POS * 2) + c16 * 16;    // + kt*128
    }

    f32x4 O[4] = {};
    float m2 = -1e30f, ell = 0.f;

    uint4 kr[2], vr[2];
#pragma unroll
    for (int i = 0; i < 2; ++i) {
        kr[i] = *(const uint4*)(kgsrc[i] + (size_t)kt0 * (KVBLK * 128));
        vr[i] = *(const uint4*)(vgsrc[i] + (size_t)kt0 * (KVBLK * 2));
    }

    for (int kt = kt0; kt < ktEnd; ++kt) {
        __syncthreads();                 // previous tile's compute done
#pragma unroll
        for (int i = 0; i < 2; ++i) {
            *(uint4*)(ksb + kdst[i]) = kr[i];
            *(uint4*)(vsb + kdst[i]) = vr[i];
        }
        __syncthreads();                 // tile ready
        if (kt + 1 < ktEnd) {            // issue next-tile loads early
#pragma unroll
            for (int i = 0; i < 2; ++i) {
                kr[i] = *(const uint4*)(kgsrc[i] + (size_t)(kt + 1) * (KVBLK * 128));
                vr[i] = *(const uint4*)(vgsrc[i] + (size_t)(kt + 1) * (KVBLK * 2));
            }
        }

        // ---- S' = K · Q^T  (S'[krow, q]) ----
        f32x4 S[4] = {};
#pragma unroll
        for (int t = 0; t < 4; ++t) {
            const int row = 16 * t + l15;
            const int sw  = row & 7;
            const short8 a0 = *(const short8*)(ksb + row * 128 + ((g ^ sw) << 4));
            const short8 a1 = *(const short8*)(ksb + row * 128 + (((g + 4) ^ sw) << 4));
            S[t] = __builtin_amdgcn_mfma_f32_16x16x32_bf16(a0, qf0, S[t], 0, 0, 0);
            S[t] = __builtin_amdgcn_mfma_f32_16x16x32_bf16(a1, qf1, S[t], 0, 0, 0);
        }

        // ---- online softmax over k for this lane's q (base-2) ----
        float pm = -1e30f;
#pragma unroll
        for (int t = 0; t < 4; ++t)
#pragma unroll
            for (int r = 0; r < 4; ++r) {
                S[t][r] *= 1.4426950408889634f;
                pm = fmaxf(pm, S[t][r]);
            }
        pm = fmaxf(pm, __shfl_xor(pm, 16));
        pm = fmaxf(pm, __shfl_xor(pm, 32));
        const float mnew  = fmaxf(m2, pm);
        const float scale = exp2f(m2 - mnew);
        float ls = 0.f;
#pragma unroll
        for (int t = 0; t < 4; ++t)
#pragma unroll
            for (int r = 0; r < 4; ++r) {
                const float pv = exp2f(S[t][r] - mnew);
                S[t][r] = pv;
                ls += pv;
            }
        ls += __shfl_xor(ls, 16);
        ls += __shfl_xor(ls, 32);
        ell = ell * scale + ls;
        m2  = mnew;
#pragma unroll
        for (int u = 0; u < 4; ++u)
#pragma unroll
            for (int r = 0; r < 4; ++r) O[u][r] *= scale;

        // ---- P -> bf16 B-fragments (in place: col = lane&15 = q already) ----
        short8 pb0, pb1;
#pragma unroll
        for (int j = 0; j < 8; ++j) {
            pb0[j] = f2bf(S[(j >> 2)][j & 3]);
            pb1[j] = f2bf(S[2 + (j >> 2)][j & 3]);
        }

        // ---- O^T += V^T · P^T ----
#pragma unroll
        for (int u = 0; u < 4; ++u) {
            const int cr = 16 * u + l15;
            const int sw = cr & 7;
            const char* vb = vsb + cr * 128 + (g & 1) * 8;
            const int gh = g >> 1;
#pragma unroll
            for (int h2 = 0; h2 < 2; ++h2) {
                const short4v v0 = *(const short4v*)(vb + (((gh + 4 * h2 + 0) ^ sw) << 4));
                const short4v v1 = *(const short4v*)(vb + (((gh + 4 * h2 + 2) ^ sw) << 4));
                const short8 vf = {v0[0], v0[1], v0[2], v0[3], v1[0], v1[1], v1[2], v1[3]};
                O[u] = __builtin_amdgcn_mfma_f32_16x16x32_bf16(vf, (h2 ? pb1 : pb0), O[u], 0, 0, 0);
            }
        }
    }

    // ---- epilogue: write un-normalized partial O, m, ell ----
    float* Op = Opart + (size_t)blockIdx.x * (QBLK * C_DIM);
    const int qlocal = wv * 16 + l15;
#pragma unroll
    for (int u = 0; u < 4; ++u)
#pragma unroll
        for (int r = 0; r < 4; ++r) {
            const int c = 16 * u + 4 * g + r;
            Op[c * QBLK + qlocal] = O[u][r];
        }
    if (g == 0) {
        float* me = mell + (size_t)blockIdx.x * 128;
        me[qlocal]      = m2;
        me[64 + qlocal] = ell;
    }
}

// ---------------------------------------------------------------------------
// Combine SPLIT partials: out = gamma * (sum_s f_s O_s) / elltot + x
// ---------------------------------------------------------------------------
template<int SPLIT>
__global__ __launch_bounds__(256) void combine_kernel(
    const float* __restrict__ Opart, const float* __restrict__ mell,
    const float* __restrict__ x, const float* __restrict__ gamma,
    float* __restrict__ out)
{
    const int bq  = blockIdx.x;
    const int b   = bq >> 6;
    const int qt  = bq & 63;
    const int row = threadIdx.x & 63;
    const int cg  = threadIdx.x >> 6;

    float m[SPLIT];
    float M = -1e30f;
#pragma unroll
    for (int s = 0; s < SPLIT; ++s) {
        m[s] = mell[((size_t)bq * SPLIT + s) * 128 + row];
        M = fmaxf(M, m[s]);
    }
    float elltot = 0.f;
#pragma unroll
    for (int s = 0; s < SPLIT; ++s) {
        m[s] = exp2f(m[s] - M);
        elltot += m[s] * mell[((size_t)bq * SPLIT + s) * 128 + 64 + row];
    }
    const float inv = gamma[0] / elltot;

#pragma unroll
    for (int ci = 0; ci < 16; ++ci) {
        const int c = cg * 16 + ci;
        float acc = 0.f;
#pragma unroll
        for (int s = 0; s < SPLIT; ++s)
            acc += m[s] * Opart[((size_t)bq * SPLIT + s) * (QBLK * C_DIM) + c * QBLK + row];
        const size_t idx = (size_t)b * C_DIM * N_POS + (size_t)c * N_POS + (size_t)(qt * QBLK + row);
        out[idx] = fmaf(inv, acc, x[idx]);
    }
}

extern "C" void kernel_launch(void* const* d_in, const int* in_sizes, int n_in,
                              void* d_out, int out_size, void* d_ws, size_t ws_size,
                              hipStream_t stream) {
    const float* x  = (const float*)d_in[0];
    const float* Wq = (const float*)d_in[1];
    const float* bq = (const float*)d_in[2];
    const float* Wk = (const float*)d_in[3];
    const float* bk = (const float*)d_in[4];
    const float* Wv = (const float*)d_in[5];
    const float* bv = (const float*)d_in[6];
    const float* gm = (const float*)d_in[7];
    float* out = (float*)d_out;

    const size_t QKV_ELEMS = (size_t)B_SZ * N_POS * C_DIM;
    ushort* Qg = (ushort*)d_ws;
    ushort* Kg = Qg + QKV_ELEMS;
    ushort* Vg = Kg + QKV_ELEMS;
    const size_t qkv_bytes = 3 * QKV_ELEMS * sizeof(ushort);

    // largest split in {4,2,1} whose partials fit in ws
    int split = 4;
    while (split > 1 &&
           qkv_bytes + (size_t)split * B_SZ * NQT * (QBLK * C_DIM + 128) * sizeof(float) > ws_size)
        split >>= 1;

    float* Opart = (float*)((char*)d_ws + qkv_bytes);
    float* mell  = Opart + (size_t)split * B_SZ * NQT * (QBLK * C_DIM);

    proj_kernel<<<B_SZ * (N_POS / 64), 512, 0, stream>>>(x, Wq, bq, Wk, bk, Wv, bv, Qg, Kg, Vg);
    attn_kernel<<<B_SZ * NQT * split, 256, 0, stream>>>(Qg, Kg, Vg, Opart, mell, split, NKV / split);
    switch (split) {
        case 4: combine_kernel<4><<<B_SZ * NQT, 256, 0, stream>>>(Opart, mell, x, gm, out); break;
        case 2: combine_kernel<2><<<B_SZ * NQT, 256, 0, stream>>>(Opart, mell, x, gm, out); break;
        default: combine_kernel<1><<<B_SZ * NQT, 256, 0, stream>>>(Opart, mell, x, gm, out); break;
    }
}